// Round 1
// baseline (950.494 us; speedup 1.0000x reference)
//
#include <hip/hip_runtime.h>

typedef unsigned short u16;
typedef __attribute__((ext_vector_type(8))) short bf16x8;
typedef __attribute__((ext_vector_type(4))) float f32x4;
typedef __attribute__((ext_vector_type(4))) u16 u16x4;

#define DEV static __device__ __forceinline__

DEV u16 f2bf(float f) {
  union { float f; unsigned u; } v; v.f = f;
  unsigned r = (v.u + 0x7fffu + ((v.u >> 16) & 1u)) >> 16;
  return (u16)r;
}

DEV void gload_lds16(const void* g, void* l) {
  __builtin_amdgcn_global_load_lds(
      (const __attribute__((address_space(1))) unsigned int*)g,
      (__attribute__((address_space(3))) unsigned int*)l, 16, 0, 0);
}

// sum over each aligned 16-lane group via DPP row rotations (pure VALU)
DEV float rowsum16(float p) {
  p += __int_as_float(__builtin_amdgcn_update_dpp(0, __float_as_int(p), 0x128, 0xF, 0xF, true)); // ror:8
  p += __int_as_float(__builtin_amdgcn_update_dpp(0, __float_as_int(p), 0x124, 0xF, 0xF, true)); // ror:4
  p += __int_as_float(__builtin_amdgcn_update_dpp(0, __float_as_int(p), 0x122, 0xF, 0xF, true)); // ror:2
  p += __int_as_float(__builtin_amdgcn_update_dpp(0, __float_as_int(p), 0x121, 0xF, 0xF, true)); // ror:1
  return p;
}

// ---------------------------------------------------------------------------
// MFMA bf16 GEMM: C[M,N] = A[M,K] * BT[N,K]^T.  M%128==0, N%128==0, K%32==0.
// EPI: 0 = store f32; 1 = +bias[col], softplus, store f32; 2 = store f32 + bf16
// ---------------------------------------------------------------------------
template<int EPI>
__global__ __launch_bounds__(256)
void gemm_bt(const u16* __restrict__ A, const u16* __restrict__ BT,
             float* __restrict__ C, u16* __restrict__ Cbf,
             const float* __restrict__ bias, int M, int N, int K) {
  __shared__ u16 As[128][32];
  __shared__ u16 Bs[128][32];
  const int t = threadIdx.x;
  const int l = t & 63;
  const int w = t >> 6;
  const int wr = (w >> 1) * 64;
  const int wc = (w & 1) * 64;
  const size_t aoff = (size_t)blockIdx.x * 128 * K;
  const size_t boff = (size_t)blockIdx.y * 128 * K;
  const int r0 = t >> 2;          // chunk row (i=0)
  const int c0 = (t & 3) * 8;     // ushort col offset within 32-wide tile row
  const int lr = l & 15;
  const int lk = (l >> 4) * 8;

  f32x4 acc[4][4];
#pragma unroll
  for (int i = 0; i < 4; ++i)
#pragma unroll
    for (int j = 0; j < 4; ++j) acc[i][j] = (f32x4){0.f, 0.f, 0.f, 0.f};

  for (int kt = 0; kt < K; kt += 32) {
    __syncthreads();
#pragma unroll
    for (int i = 0; i < 2; ++i) {
      const int r = r0 + i * 64;
      gload_lds16(A + aoff + (size_t)r * K + kt + c0, &As[r][c0]);
      gload_lds16(BT + boff + (size_t)r * K + kt + c0, &Bs[r][c0]);
    }
    __syncthreads();
    bf16x8 af[4], bfr[4];
#pragma unroll
    for (int i = 0; i < 4; ++i) af[i] = *(const bf16x8*)&As[wr + i * 16 + lr][lk];
#pragma unroll
    for (int j = 0; j < 4; ++j) bfr[j] = *(const bf16x8*)&Bs[wc + j * 16 + lr][lk];
#pragma unroll
    for (int i = 0; i < 4; ++i)
#pragma unroll
      for (int j = 0; j < 4; ++j)
        acc[i][j] = __builtin_amdgcn_mfma_f32_16x16x32_bf16(af[i], bfr[j], acc[i][j], 0, 0, 0);
  }

  const int lg4 = (l >> 4) * 4;
#pragma unroll
  for (int i = 0; i < 4; ++i) {
    const int grow0 = blockIdx.x * 128 + wr + i * 16 + lg4;
#pragma unroll
    for (int j = 0; j < 4; ++j) {
      const int gcol = blockIdx.y * 128 + wc + j * 16 + lr;
      float bv = 0.f;
      if (EPI == 1) bv = bias[gcol];
#pragma unroll
      for (int r = 0; r < 4; ++r) {
        float v = acc[i][j][r];
        if (EPI == 1) {
          v += bv;
          v = fmaxf(v, 0.f) + log1pf(expf(-fabsf(v)));   // stable softplus (== jax)
        }
        const size_t idx = (size_t)(grow0 + r) * N + gcol;
        C[idx] = v;
        if (EPI == 2) Cbf[idx] = f2bf(v);
      }
    }
  }
}

// ---------------------------------------------------------------------------
// transpose+convert: in f32 (K,N) -> out bf16 (Npad,K), zero-pad rows n>=N.
// grid (K/32, Npad/32), block 256.
// ---------------------------------------------------------------------------
__global__ __launch_bounds__(256)
void transpose_bf(const float* __restrict__ in, u16* __restrict__ out, int K, int N) {
  __shared__ float tile[32][33];
  const int kb = blockIdx.x * 32;
  const int nb = blockIdx.y * 32;
  const int tx = threadIdx.x & 31;
  const int ty = threadIdx.x >> 5;   // 0..7
#pragma unroll
  for (int s = 0; s < 4; ++s) {
    const int k = kb + ty + s * 8;
    const int n = nb + tx;
    tile[ty + s * 8][tx] = (n < N) ? in[(size_t)k * N + n] : 0.f;
  }
  __syncthreads();
#pragma unroll
  for (int s = 0; s < 4; ++s) {
    const int n = nb + ty + s * 8;
    const int k = kb + tx;
    out[(size_t)n * K + k] = f2bf(tile[tx][ty + s * 8]);
  }
}

__global__ __launch_bounds__(256)
void embed_gather(const int* __restrict__ ids, const float* __restrict__ embed,
                  u16* __restrict__ xbf) {
  const int r = blockIdx.x;
  const int c = threadIdx.x * 4;
  const int id = ids[r];
  const float4 v = *(const float4*)(embed + (size_t)id * 1024 + c);
  u16x4 o = { f2bf(v.x), f2bf(v.y), f2bf(v.z), f2bf(v.w) };
  *(u16x4*)(xbf + (size_t)r * 1024 + c) = o;
}

// u = silu(causal_conv(xin) + cb); writes f32 and bf16.  idx = r*2048+d
__global__ __launch_bounds__(256)
void conv_silu(const float* __restrict__ xz, const float* __restrict__ cw,
               const float* __restrict__ cb, float* __restrict__ u,
               u16* __restrict__ ubf) {
  const int idx = blockIdx.x * 256 + threadIdx.x;
  const int d = idx & 2047;
  const int r = idx >> 11;
  const int t = r & 1023;
  const float4 wv = *(const float4*)(cw + d * 4);
  float a = cb[d];
  if (t >= 3) {
    const float* p = xz + (size_t)(r - 3) * 4096 + d;
    a += p[0] * wv.x + p[4096] * wv.y + p[8192] * wv.z + p[12288] * wv.w;
  } else {
    const float wk[4] = { wv.x, wv.y, wv.z, wv.w };
#pragma unroll
    for (int k = 0; k < 4; ++k) {
      const int tt = t - 3 + k;
      if (tt >= 0) a += xz[(size_t)(r - 3 + k) * 4096 + d] * wk[k];
    }
  }
  const float s = a / (1.f + __expf(-a));
  u[idx] = s;
  ubf[idx] = f2bf(s);
}

__global__ __launch_bounds__(256)
void extract_dt(const float* __restrict__ dbc, u16* __restrict__ dtbf) {
  const int idx = blockIdx.x * 256 + threadIdx.x;   // 2048*64
  const int r = idx >> 6, c = idx & 63;
  dtbf[idx] = f2bf(dbc[(size_t)r * 128 + c]);
}

// ---------------------------------------------------------------------------
// selective scan, fused y = (sum_n h*C + u*D) * silu(z), bf16 out.
// thread = (n = tid&15, dl = tid>>4); block = (b, 16-wide d tile); grid 256.
// ---------------------------------------------------------------------------
__global__ __launch_bounds__(256)
void mamba_scan(const float* __restrict__ delta, const float* __restrict__ u,
                const float* __restrict__ dbc, const float* __restrict__ xz,
                const float* __restrict__ A_log, const float* __restrict__ Dp,
                u16* __restrict__ ybf) {
  const int blk = blockIdx.x;
  const int b = blk >> 7;
  const int dt16 = blk & 127;
  const int n = threadIdx.x & 15;
  const int dl = threadIdx.x >> 4;
  const int d = dt16 * 16 + dl;
  const float Ac = -expf(A_log[d * 16 + n]) * 1.44269504f;  // * log2(e) for exp2
  const float Dd = Dp[d];
  const int r0 = b << 10;
  float h = 0.f;

  float pdA[8], puA[8], pBA[8], pCA[8], pzA[8];
  float pdB[8], puB[8], pBB[8], pCB[8], pzB[8];

#define LOADG(S, g) { const int rr = r0 + (g) * 8;                              \
  _Pragma("unroll") for (int j = 0; j < 8; ++j) { const size_t r = rr + j;      \
    pd##S[j] = delta[r * 2048 + d];  pu##S[j] = u[r * 2048 + d];                \
    pB##S[j] = dbc[r * 128 + 64 + n]; pC##S[j] = dbc[r * 128 + 80 + n];         \
    pz##S[j] = xz[r * 4096 + 2048 + d]; } }

#define COMPG(S, g) { _Pragma("unroll") for (int j = 0; j < 8; ++j) {           \
    const float dlt = pd##S[j]; const float uu = pu##S[j];                      \
    const float da = exp2f(dlt * Ac);                                           \
    h = fmaf(da, h, dlt * uu * pB##S[j]);                                       \
    float p = h * pC##S[j];                                                     \
    p = rowsum16(p);                                                            \
    if (n == 0) {                                                               \
      const float zz = pz##S[j];                                                \
      const float yv = (p + uu * Dd) * (zz / (1.f + __expf(-zz)));              \
      ybf[(size_t)(r0 + (g) * 8 + j) * 2048 + d] = f2bf(yv);                    \
    } } }

  LOADG(A, 0)
  for (int g = 0; g < 128; g += 2) {
    LOADG(B, g + 1)
    COMPG(A, g)
    if (g + 2 < 128) LOADG(A, g + 2)
    COMPG(B, g + 1)
  }
#undef LOADG
#undef COMPG
}

// layernorm over 1024, writes bf16.  one wave per row; block = 4 rows.
__global__ __launch_bounds__(256)
void ln_bf(const float* __restrict__ x, const float* __restrict__ g,
           const float* __restrict__ b, u16* __restrict__ out) {
  const int r = blockIdx.x * 4 + (threadIdx.x >> 6);
  const int l = threadIdx.x & 63;
  const float4* xr = (const float4*)(x + (size_t)r * 1024);
  float4 v[4];
  float s = 0.f;
#pragma unroll
  for (int i = 0; i < 4; ++i) {
    v[i] = xr[i * 64 + l];
    s += v[i].x + v[i].y + v[i].z + v[i].w;
  }
#pragma unroll
  for (int m = 1; m < 64; m <<= 1) s += __shfl_xor(s, m, 64);
  const float mu = s * (1.f / 1024.f);
  float q = 0.f;
#pragma unroll
  for (int i = 0; i < 4; ++i) {
    float a0 = v[i].x - mu, a1 = v[i].y - mu, a2 = v[i].z - mu, a3 = v[i].w - mu;
    q += a0 * a0 + a1 * a1 + a2 * a2 + a3 * a3;
  }
#pragma unroll
  for (int m = 1; m < 64; m <<= 1) q += __shfl_xor(q, m, 64);
  const float rs = rsqrtf(q * (1.f / 1024.f) + 1e-5f);
#pragma unroll
  for (int i = 0; i < 4; ++i) {
    const int c = (i * 64 + l) * 4;
    const float4 gv = *(const float4*)(g + c);
    const float4 bv = *(const float4*)(b + c);
    u16x4 o = { f2bf((v[i].x - mu) * rs * gv.x + bv.x),
                f2bf((v[i].y - mu) * rs * gv.y + bv.y),
                f2bf((v[i].z - mu) * rs * gv.z + bv.z),
                f2bf((v[i].w - mu) * rs * gv.w + bv.w) };
    *(u16x4*)(out + (size_t)r * 1024 + c) = o;
  }
}

// ---------------------------------------------------------------------------
extern "C" void kernel_launch(void* const* d_in, const int* in_sizes, int n_in,
                              void* d_out, int out_size, void* d_ws, size_t ws_size,
                              hipStream_t stream) {
  (void)in_sizes; (void)n_in; (void)out_size; (void)ws_size;
  const int*   ids      = (const int*)d_in[0];
  const float* embed    = (const float*)d_in[1];
  const float* in_proj  = (const float*)d_in[2];
  const float* conv_w   = (const float*)d_in[3];
  const float* conv_b   = (const float*)d_in[4];
  const float* x_proj   = (const float*)d_in[5];
  const float* dt_w     = (const float*)d_in[6];
  const float* dt_b     = (const float*)d_in[7];
  const float* A_log    = (const float*)d_in[8];
  const float* Dp       = (const float*)d_in[9];
  const float* out_proj = (const float*)d_in[10];
  const float* ln_g     = (const float*)d_in[11];
  const float* ln_bta   = (const float*)d_in[12];
  const float* head     = (const float*)d_in[13];

  // f32 scratch inside d_out (65,536,000 floats; all consumed before head GEMM)
  float* fout = (float*)d_out;
  float* xz   = fout;              // 2048*4096
  float* ubuf = fout + 8388608;    // 2048*2048
  float* dbuf = fout + 12582912;   // 2048*2048 (delta)
  float* dbc  = fout + 16777216;   // 2048*128
  float* xf   = fout + 17039360;   // 2048*1024

  // bf16 scratch in d_ws (~104.4 MB)
  char* wp = (char*)d_ws;
  u16* headT = (u16*)wp; wp += (size_t)32000 * 1024 * 2;
  u16* WiT   = (u16*)wp; wp += (size_t)4096 * 1024 * 2;
  u16* WxT   = (u16*)wp; wp += (size_t)128 * 2048 * 2;
  u16* WdtT  = (u16*)wp; wp += (size_t)2048 * 64 * 2;
  u16* WoT   = (u16*)wp; wp += (size_t)1024 * 2048 * 2;
  u16* xbf   = (u16*)wp; wp += (size_t)2048 * 1024 * 2;
  u16* ubf   = (u16*)wp; wp += (size_t)2048 * 2048 * 2;
  u16* dtbf  = (u16*)wp; wp += (size_t)2048 * 64 * 2;
  u16* ybf   = (u16*)wp; wp += (size_t)2048 * 2048 * 2;
  u16* xlnbf = (u16*)wp; wp += (size_t)2048 * 1024 * 2;

  const dim3 tb(256);
  embed_gather<<<2048, tb, 0, stream>>>(ids, embed, xbf);

  for (int i = 0; i < 2; ++i) {
    transpose_bf<<<dim3(32, 128), tb, 0, stream>>>(in_proj + (size_t)i * 1024 * 4096, WiT, 1024, 4096);
    transpose_bf<<<dim3(64, 4),   tb, 0, stream>>>(x_proj + (size_t)i * 2048 * 96,   WxT, 2048, 96);
    transpose_bf<<<dim3(2, 64),   tb, 0, stream>>>(dt_w + (size_t)i * 64 * 2048,     WdtT, 64, 2048);
    transpose_bf<<<dim3(64, 32),  tb, 0, stream>>>(out_proj + (size_t)i * 2048 * 1024, WoT, 2048, 1024);

    gemm_bt<0><<<dim3(16, 32), tb, 0, stream>>>(xbf, WiT, xz, nullptr, nullptr, 2048, 4096, 1024);
    conv_silu<<<16384, tb, 0, stream>>>(xz, conv_w + i * 2048 * 4, conv_b + i * 2048, ubuf, ubf);
    gemm_bt<0><<<dim3(16, 1), tb, 0, stream>>>(ubf, WxT, dbc, nullptr, nullptr, 2048, 128, 2048);
    extract_dt<<<512, tb, 0, stream>>>(dbc, dtbf);
    gemm_bt<1><<<dim3(16, 16), tb, 0, stream>>>(dtbf, WdtT, dbuf, nullptr, dt_b + i * 2048, 2048, 2048, 64);
    mamba_scan<<<256, tb, 0, stream>>>(dbuf, ubuf, dbc, xz, A_log + i * 2048 * 16, Dp + i * 2048, ybf);
    gemm_bt<2><<<dim3(16, 8), tb, 0, stream>>>(ybf, WoT, xf, xbf, nullptr, 2048, 1024, 2048);
  }

  ln_bf<<<512, tb, 0, stream>>>(xf, ln_g, ln_bta, xlnbf);
  transpose_bf<<<dim3(32, 1000), tb, 0, stream>>>(head, headT, 1024, 32000);
  gemm_bt<0><<<dim3(16, 250), tb, 0, stream>>>(xlnbf, headT, fout, nullptr, nullptr, 2048, 32000, 1024);
}

// Round 2
// 894.196 us; speedup vs baseline: 1.0630x; 1.0630x over previous
//
#include <hip/hip_runtime.h>

typedef unsigned short u16;
typedef __attribute__((ext_vector_type(8))) short bf16x8;
typedef __attribute__((ext_vector_type(4))) float f32x4;
typedef __attribute__((ext_vector_type(4))) u16 u16x4;

#define DEV static __device__ __forceinline__

DEV u16 f2bf(float f) {
  union { float f; unsigned u; } v; v.f = f;
  unsigned r = (v.u + 0x7fffu + ((v.u >> 16) & 1u)) >> 16;
  return (u16)r;
}

DEV void gload_lds16(const void* g, void* l) {
  __builtin_amdgcn_global_load_lds(
      (const __attribute__((address_space(1))) unsigned int*)g,
      (__attribute__((address_space(3))) unsigned int*)l, 16, 0, 0);
}

// sum over each aligned 16-lane group via DPP row rotations (pure VALU)
DEV float rowsum16(float p) {
  p += __int_as_float(__builtin_amdgcn_update_dpp(0, __float_as_int(p), 0x128, 0xF, 0xF, true)); // ror:8
  p += __int_as_float(__builtin_amdgcn_update_dpp(0, __float_as_int(p), 0x124, 0xF, 0xF, true)); // ror:4
  p += __int_as_float(__builtin_amdgcn_update_dpp(0, __float_as_int(p), 0x122, 0xF, 0xF, true)); // ror:2
  p += __int_as_float(__builtin_amdgcn_update_dpp(0, __float_as_int(p), 0x121, 0xF, 0xF, true)); // ror:1
  return p;
}

// ---------------------------------------------------------------------------
// MFMA bf16 GEMM: C[M,N] = A[M,K] * BT[N,K]^T.  M%128==0, N%128==0, K%64==0.
// BK=64 tile with XOR-swizzled LDS (linear dest for global_load_lds, inverse-
// swizzled global source, swizzled ds_read) -> conflict-free b128 reads.
// gridDim.x MUST be 16; nwg % 8 == 0 (bijective XCD chunking).
// EPI: 0 = f32; 1 = +bias, softplus, f32; 2 = f32 + bf16; 3 = f32 + bf16 of
//      cols<64 into Cbf with row stride 64 (fused dt extract).
// ---------------------------------------------------------------------------
template<int EPI>
__global__ __launch_bounds__(256)
void gemm_bt(const u16* __restrict__ A, const u16* __restrict__ BT,
             float* __restrict__ C, u16* __restrict__ Cbf,
             const float* __restrict__ bias, int M, int N, int K) {
  __shared__ u16 As[128][64];
  __shared__ u16 Bs[128][64];
  const int t = threadIdx.x;
  const int l = t & 63;
  const int w = t >> 6;
  const int wr = (w >> 1) * 64;
  const int wc = (w & 1) * 64;

  // XCD-chunked bijective block swizzle (nwg % 8 == 0 for all call sites)
  const int nwg = gridDim.x * gridDim.y;
  const int orig = blockIdx.y * gridDim.x + blockIdx.x;
  const int swz = (orig & 7) * (nwg >> 3) + (orig >> 3);
  const int bx = swz & 15;          // gridDim.x == 16 always
  const int by = swz >> 4;

  const size_t aoff = (size_t)bx * 128 * K;
  const size_t boff = (size_t)by * 128 * K;
  const int r0 = t >> 3;                          // 0..31 (4 rounds of 32 rows)
  const int c0s = (((t & 7) ^ (r0 & 7)) << 3);    // inverse-swizzled source col
  const int c0l = (t & 7) << 3;                   // linear LDS col
  const int lr = l & 15;
  const int lq = l >> 4;                          // 0..3

  f32x4 acc[4][4];
#pragma unroll
  for (int i = 0; i < 4; ++i)
#pragma unroll
    for (int j = 0; j < 4; ++j) acc[i][j] = (f32x4){0.f, 0.f, 0.f, 0.f};

  for (int kt = 0; kt < K; kt += 64) {
    __syncthreads();
#pragma unroll
    for (int i = 0; i < 4; ++i) {
      const int r = r0 + i * 32;
      gload_lds16(A + aoff + (size_t)r * K + kt + c0s, &As[r][c0l]);
      gload_lds16(BT + boff + (size_t)r * K + kt + c0s, &Bs[r][c0l]);
    }
    __syncthreads();
#pragma unroll
    for (int kk = 0; kk < 2; ++kk) {
      bf16x8 af[4], bfr[4];
#pragma unroll
      for (int i = 0; i < 4; ++i) {
        const int row = wr + i * 16 + lr;
        af[i] = *(const bf16x8*)&As[row][(((kk << 2) | lq) ^ (row & 7)) << 3];
      }
#pragma unroll
      for (int j = 0; j < 4; ++j) {
        const int row = wc + j * 16 + lr;
        bfr[j] = *(const bf16x8*)&Bs[row][(((kk << 2) | lq) ^ (row & 7)) << 3];
      }
#pragma unroll
      for (int i = 0; i < 4; ++i)
#pragma unroll
        for (int j = 0; j < 4; ++j)
          acc[i][j] = __builtin_amdgcn_mfma_f32_16x16x32_bf16(af[i], bfr[j], acc[i][j], 0, 0, 0);
    }
  }

  const int lg4 = lq * 4;
#pragma unroll
  for (int i = 0; i < 4; ++i) {
    const int grow0 = bx * 128 + wr + i * 16 + lg4;
#pragma unroll
    for (int j = 0; j < 4; ++j) {
      const int gcol = by * 128 + wc + j * 16 + lr;
      float bv = 0.f;
      if (EPI == 1) bv = bias[gcol];
#pragma unroll
      for (int r = 0; r < 4; ++r) {
        float v = acc[i][j][r];
        if (EPI == 1) {
          v += bv;
          v = fmaxf(v, 0.f) + log1pf(expf(-fabsf(v)));   // stable softplus
        }
        const size_t idx = (size_t)(grow0 + r) * N + gcol;
        C[idx] = v;
        if (EPI == 2) Cbf[idx] = f2bf(v);
        if (EPI == 3 && gcol < 64) Cbf[(size_t)(grow0 + r) * 64 + gcol] = f2bf(v);
      }
    }
  }
}

// ---------------------------------------------------------------------------
// batched transpose+convert: f32 (K,N) -> bf16 (Npad,K), zero-pad n>=N.
// up to 5 jobs per launch; one 32x32 tile per block.
// ---------------------------------------------------------------------------
struct TBatch {
  const float* src[5];
  u16* dst[5];
  int K[5], N[5], tx[5];
  int start[6];
  int njobs;
};

__global__ __launch_bounds__(256)
void transpose_batch(TBatch tb) {
  const int tile = blockIdx.x;
  int j = 0;
  while (j + 1 < tb.njobs && tile >= tb.start[j + 1]) ++j;
  const int lt = tile - tb.start[j];
  const int K = tb.K[j];
  const int N = tb.N[j];
  const int kb = (lt % tb.tx[j]) * 32;
  const int nb = (lt / tb.tx[j]) * 32;
  const float* __restrict__ in = tb.src[j];
  u16* __restrict__ out = tb.dst[j];

  __shared__ float tile_s[32][33];
  const int tx = threadIdx.x & 31;
  const int ty = threadIdx.x >> 5;   // 0..7
#pragma unroll
  for (int s = 0; s < 4; ++s) {
    const int k = kb + ty + s * 8;
    const int n = nb + tx;
    tile_s[ty + s * 8][tx] = (n < N) ? in[(size_t)k * N + n] : 0.f;
  }
  __syncthreads();
#pragma unroll
  for (int s = 0; s < 4; ++s) {
    const int n = nb + ty + s * 8;
    const int k = kb + tx;
    out[(size_t)n * K + k] = f2bf(tile_s[tx][ty + s * 8]);
  }
}

__global__ __launch_bounds__(256)
void embed_gather(const int* __restrict__ ids, const float* __restrict__ embed,
                  u16* __restrict__ xbf) {
  const int r = blockIdx.x;
  const int c = threadIdx.x * 4;
  const int id = ids[r];
  const float4 v = *(const float4*)(embed + (size_t)id * 1024 + c);
  u16x4 o = { f2bf(v.x), f2bf(v.y), f2bf(v.z), f2bf(v.w) };
  *(u16x4*)(xbf + (size_t)r * 1024 + c) = o;
}

// u = silu(causal_conv(xin) + cb); writes f32 and bf16.  idx = r*2048+d
__global__ __launch_bounds__(256)
void conv_silu(const float* __restrict__ xz, const float* __restrict__ cw,
               const float* __restrict__ cb, float* __restrict__ u,
               u16* __restrict__ ubf) {
  const int idx = blockIdx.x * 256 + threadIdx.x;
  const int d = idx & 2047;
  const int r = idx >> 11;
  const int t = r & 1023;
  const float4 wv = *(const float4*)(cw + d * 4);
  float a = cb[d];
  if (t >= 3) {
    const float* p = xz + (size_t)(r - 3) * 4096 + d;
    a += p[0] * wv.x + p[4096] * wv.y + p[8192] * wv.z + p[12288] * wv.w;
  } else {
    const float wk[4] = { wv.x, wv.y, wv.z, wv.w };
#pragma unroll
    for (int k = 0; k < 4; ++k) {
      const int tt = t - 3 + k;
      if (tt >= 0) a += xz[(size_t)(r - 3 + k) * 4096 + d] * wk[k];
    }
  }
  const float s = a / (1.f + __expf(-a));
  u[idx] = s;
  ubf[idx] = f2bf(s);
}

// ---------------------------------------------------------------------------
// chunked selective scan: 8 chunks x 128 steps.
// pass1: per-chunk P = prod(dA), Q = local scan with h0=0 (no y).
// pass2: h_init = fold(P,Q over earlier chunks), full scan with y output.
// block = 256 thr (n = t&15, dl = t>>4); grid = B(2) * dtile(128) * ch(8).
// ---------------------------------------------------------------------------
__global__ __launch_bounds__(256)
void scan_pass1(const float* __restrict__ delta, const float* __restrict__ u,
                const float* __restrict__ dbc, const float* __restrict__ A_log,
                float* __restrict__ Pb, float* __restrict__ Qb) {
  const int blk = blockIdx.x;
  const int ch = blk & 7;
  const int dt16 = (blk >> 3) & 127;
  const int b = blk >> 10;
  const int n = threadIdx.x & 15;
  const int dl = threadIdx.x >> 4;
  const int d = dt16 * 16 + dl;
  const float Ac = -expf(A_log[d * 16 + n]) * 1.44269504f;
  const int r0 = b * 1024 + ch * 128;
  float P = 1.f, h = 0.f;
  for (int j = 0; j < 128; ++j) {
    const size_t r = r0 + j;
    const float dlt = delta[r * 2048 + d];
    const float uu = u[r * 2048 + d];
    const float Bv = dbc[r * 128 + 64 + n];
    const float da = exp2f(dlt * Ac);
    P *= da;
    h = fmaf(da, h, dlt * uu * Bv);
  }
  const size_t idx = ((size_t)(b * 2048 + d) * 16 + n) * 8 + ch;
  Pb[idx] = P;
  Qb[idx] = h;
}

__global__ __launch_bounds__(256)
void scan_pass2(const float* __restrict__ delta, const float* __restrict__ u,
                const float* __restrict__ dbc, const float* __restrict__ xz,
                const float* __restrict__ A_log, const float* __restrict__ Dp,
                const float* __restrict__ Pb, const float* __restrict__ Qb,
                u16* __restrict__ ybf) {
  const int blk = blockIdx.x;
  const int ch = blk & 7;
  const int dt16 = (blk >> 3) & 127;
  const int b = blk >> 10;
  const int n = threadIdx.x & 15;
  const int dl = threadIdx.x >> 4;
  const int d = dt16 * 16 + dl;
  const float Ac = -expf(A_log[d * 16 + n]) * 1.44269504f;
  const float Dd = Dp[d];
  const int r0 = b * 1024 + ch * 128;

  float h = 0.f;
  const size_t p0 = ((size_t)(b * 2048 + d) * 16 + n) * 8;
  for (int cc = 0; cc < ch; ++cc) h = fmaf(Pb[p0 + cc], h, Qb[p0 + cc]);

  for (int j = 0; j < 128; ++j) {
    const size_t r = r0 + j;
    const float dlt = delta[r * 2048 + d];
    const float uu = u[r * 2048 + d];
    const float Bv = dbc[r * 128 + 64 + n];
    const float Cv = dbc[r * 128 + 80 + n];
    const float da = exp2f(dlt * Ac);
    h = fmaf(da, h, dlt * uu * Bv);
    float p = rowsum16(h * Cv);
    if (n == 0) {
      const float zz = xz[r * 4096 + 2048 + d];
      const float yv = (p + uu * Dd) * (zz / (1.f + __expf(-zz)));
      ybf[r * 2048 + d] = f2bf(yv);
    }
  }
}

// layernorm over 1024, writes bf16.  one wave per row; block = 4 rows.
__global__ __launch_bounds__(256)
void ln_bf(const float* __restrict__ x, const float* __restrict__ g,
           const float* __restrict__ b, u16* __restrict__ out) {
  const int r = blockIdx.x * 4 + (threadIdx.x >> 6);
  const int l = threadIdx.x & 63;
  const float4* xr = (const float4*)(x + (size_t)r * 1024);
  float4 v[4];
  float s = 0.f;
#pragma unroll
  for (int i = 0; i < 4; ++i) {
    v[i] = xr[i * 64 + l];
    s += v[i].x + v[i].y + v[i].z + v[i].w;
  }
#pragma unroll
  for (int m = 1; m < 64; m <<= 1) s += __shfl_xor(s, m, 64);
  const float mu = s * (1.f / 1024.f);
  float q = 0.f;
#pragma unroll
  for (int i = 0; i < 4; ++i) {
    float a0 = v[i].x - mu, a1 = v[i].y - mu, a2 = v[i].z - mu, a3 = v[i].w - mu;
    q += a0 * a0 + a1 * a1 + a2 * a2 + a3 * a3;
  }
#pragma unroll
  for (int m = 1; m < 64; m <<= 1) q += __shfl_xor(q, m, 64);
  const float rs = rsqrtf(q * (1.f / 1024.f) + 1e-5f);
#pragma unroll
  for (int i = 0; i < 4; ++i) {
    const int c = (i * 64 + l) * 4;
    const float4 gv = *(const float4*)(g + c);
    const float4 bv = *(const float4*)(b + c);
    u16x4 o = { f2bf((v[i].x - mu) * rs * gv.x + bv.x),
                f2bf((v[i].y - mu) * rs * gv.y + bv.y),
                f2bf((v[i].z - mu) * rs * gv.z + bv.z),
                f2bf((v[i].w - mu) * rs * gv.w + bv.w) };
    *(u16x4*)(out + (size_t)r * 1024 + c) = o;
  }
}

// ---------------------------------------------------------------------------
extern "C" void kernel_launch(void* const* d_in, const int* in_sizes, int n_in,
                              void* d_out, int out_size, void* d_ws, size_t ws_size,
                              hipStream_t stream) {
  (void)in_sizes; (void)n_in; (void)out_size; (void)ws_size;
  const int*   ids      = (const int*)d_in[0];
  const float* embed    = (const float*)d_in[1];
  const float* in_proj  = (const float*)d_in[2];
  const float* conv_w   = (const float*)d_in[3];
  const float* conv_b   = (const float*)d_in[4];
  const float* x_proj   = (const float*)d_in[5];
  const float* dt_w     = (const float*)d_in[6];
  const float* dt_b     = (const float*)d_in[7];
  const float* A_log    = (const float*)d_in[8];
  const float* Dp       = (const float*)d_in[9];
  const float* out_proj = (const float*)d_in[10];
  const float* ln_g     = (const float*)d_in[11];
  const float* ln_bta   = (const float*)d_in[12];
  const float* head     = (const float*)d_in[13];

  // f32 scratch inside d_out (65,536,000 floats; all consumed before head GEMM)
  float* fout = (float*)d_out;
  float* xz   = fout;              // 2048*4096
  float* ubuf = fout + 8388608;    // 2048*2048
  float* dbuf = fout + 12582912;   // 2048*2048 (delta)
  float* dbc  = fout + 16777216;   // 2048*128
  float* xf   = fout + 17039360;   // 2048*1024
  float* Pb   = fout + 19136512;   // 2048*2048*... (2*2048*16*8 = 524288)
  float* Qb   = fout + 19660800;   // 524288

  // bf16 scratch in d_ws (~104.4 MB)
  char* wp = (char*)d_ws;
  u16* headT = (u16*)wp; wp += (size_t)32000 * 1024 * 2;
  u16* WiT   = (u16*)wp; wp += (size_t)4096 * 1024 * 2;
  u16* WxT   = (u16*)wp; wp += (size_t)128 * 2048 * 2;
  u16* WdtT  = (u16*)wp; wp += (size_t)2048 * 64 * 2;
  u16* WoT   = (u16*)wp; wp += (size_t)1024 * 2048 * 2;
  u16* xbf   = (u16*)wp; wp += (size_t)2048 * 1024 * 2;
  u16* ubf   = (u16*)wp; wp += (size_t)2048 * 2048 * 2;
  u16* dtbf  = (u16*)wp; wp += (size_t)2048 * 64 * 2;
  u16* ybf   = (u16*)wp; wp += (size_t)2048 * 2048 * 2;
  u16* xlnbf = (u16*)wp; wp += (size_t)2048 * 1024 * 2;

  const dim3 tb(256);
  embed_gather<<<2048, tb, 0, stream>>>(ids, embed, xbf);

  for (int i = 0; i < 2; ++i) {
    // batched transposes: layer-i weights (+ head on first launch)
    TBatch t{};
    int nj = 0, acc = 0;
    if (i == 0) {
      t.src[nj] = head; t.dst[nj] = headT;
      t.K[nj] = 1024; t.N[nj] = 32000; t.tx[nj] = 32;
      t.start[nj] = acc; acc += 32 * 1000; ++nj;
    }
    t.src[nj] = in_proj + (size_t)i * 1024 * 4096; t.dst[nj] = WiT;
    t.K[nj] = 1024; t.N[nj] = 4096; t.tx[nj] = 32;
    t.start[nj] = acc; acc += 32 * 128; ++nj;
    t.src[nj] = x_proj + (size_t)i * 2048 * 96; t.dst[nj] = WxT;
    t.K[nj] = 2048; t.N[nj] = 96; t.tx[nj] = 64;
    t.start[nj] = acc; acc += 64 * 4; ++nj;
    t.src[nj] = dt_w + (size_t)i * 64 * 2048; t.dst[nj] = WdtT;
    t.K[nj] = 64; t.N[nj] = 2048; t.tx[nj] = 2;
    t.start[nj] = acc; acc += 2 * 64; ++nj;
    t.src[nj] = out_proj + (size_t)i * 2048 * 1024; t.dst[nj] = WoT;
    t.K[nj] = 2048; t.N[nj] = 1024; t.tx[nj] = 64;
    t.start[nj] = acc; acc += 64 * 32; ++nj;
    t.start[nj] = acc;
    t.njobs = nj;
    transpose_batch<<<acc, tb, 0, stream>>>(t);

    gemm_bt<0><<<dim3(16, 32), tb, 0, stream>>>(xbf, WiT, xz, nullptr, nullptr, 2048, 4096, 1024);
    conv_silu<<<16384, tb, 0, stream>>>(xz, conv_w + i * 2048 * 4, conv_b + i * 2048, ubuf, ubf);
    gemm_bt<3><<<dim3(16, 1), tb, 0, stream>>>(ubf, WxT, dbc, dtbf, nullptr, 2048, 128, 2048);
    gemm_bt<1><<<dim3(16, 16), tb, 0, stream>>>(dtbf, WdtT, dbuf, nullptr, dt_b + i * 2048, 2048, 2048, 64);
    scan_pass1<<<2048, tb, 0, stream>>>(dbuf, ubuf, dbc, A_log + i * 2048 * 16, Pb, Qb);
    scan_pass2<<<2048, tb, 0, stream>>>(dbuf, ubuf, dbc, xz, A_log + i * 2048 * 16, Dp + i * 2048, Pb, Qb, ybf);
    gemm_bt<2><<<dim3(16, 8), tb, 0, stream>>>(ybf, WoT, xf, xbf, nullptr, 2048, 1024, 2048);
  }

  ln_bf<<<512, tb, 0, stream>>>(xf, ln_g, ln_bta, xlnbf);
  gemm_bt<0><<<dim3(16, 250), tb, 0, stream>>>(xlnbf, headT, fout, nullptr, nullptr, 2048, 32000, 1024);
}